// Round 8
// baseline (1063.854 us; speedup 1.0000x reference)
//
#include <hip/hip_runtime.h>
#include <stdint.h>

#define BM 256
#define BN 256
#define BKB 64             // K-bytes (i8 elems) per tile

typedef __attribute__((ext_vector_type(4)))  int i32x4;
typedef __attribute__((ext_vector_type(16))) int i32x16;

__device__ __forceinline__ void async16(const void* g, void* l) {
    __builtin_amdgcn_global_load_lds(
        (const __attribute__((address_space(1))) unsigned int*)g,
        (__attribute__((address_space(3))) unsigned int*)l,
        16 /*bytes*/, 0 /*offset*/, 0 /*aux*/);
}

// Pack int32 (one int8 value per int) -> int8 bytes. Coalesced both sides.
__global__ void pack_both(const int4* __restrict__ sx, int* __restrict__ dx, int nx4,
                          const int4* __restrict__ sw, int* __restrict__ dw, int nw4) {
    int idx    = blockIdx.x * blockDim.x + threadIdx.x;
    int stride = gridDim.x * blockDim.x;
    for (int i = idx; i < nx4; i += stride) {
        int4 a = sx[i];
        dx[i] = (a.x & 0xFF) | ((a.y & 0xFF) << 8) | ((a.z & 0xFF) << 16) | (a.w << 24);
    }
    for (int i = idx; i < nw4; i += stride) {
        int4 a = sw[i];
        dw[i] = (a.x & 0xFF) | ((a.y & 0xFF) << 8) | ((a.z & 0xFF) << 16) | (a.w << 24);
    }
}

// 256x256 tile, BK=64, 8 waves (2M x 4N), per-wave 128x64 via 4x2 mfma_i32_32x32x32_i8.
// Round-6: 4-deep LDS ring (4 x 32 KB = 128 KiB) + DERIVED COUNTED vmcnt (T4, m218):
//   prefetch tile t+3 at the top of tile t; steady-state wait is vmcnt(12) -- the 3
//   newer tiles' 4 loads/wave may remain in flight; tile t's 4 oldest have landed.
//   NEVER vmcnt(0) in the main loop (tail peels 12->8->4->0). ~3 tiles (~3500 cyc) of
//   slack covers HBM latency + DMA queue. One drain-free s_barrier per tile keeps waves
//   within one tile of each other (buffer-overwrite hazard: STAGE(t+3) writes
//   buf[(t-1)&3]; all waves' t-1 ds_reads are lgkm-consumed by their MFMAs before the
//   barrier). sched_barrier(0) after s_barrier pins STAGE ordering (s_barrier builtin is
//   not an LLVM memory fence).
// Swizzle (64-B rows, pigeonhole-optimal): phys_chunk = (logical + (row>>1)) & 3.
//   Uniform 4 lanes per 16B bank-slot on ds_read_b128 (XOR-by-(row&3) would be 8-way).
//   Inverse applied on global source (linear gload_lds dest), additive on ds_read addr.
// MFMA 32x32x32 i8 frags: lane = [row/col = lane&31][k-half = lane>>5], 16 B.
// C/D: col = lane&31, row = (reg&3) + 8*(reg>>2) + 4*(lane>>5)  (HW-verified).
__global__ __launch_bounds__(512, 2) void w8a8_silu_kernel(
    const int8_t* __restrict__ x, const int8_t* __restrict__ w,
    const float* __restrict__ bias, const float* __restrict__ alpha_p,
    float* __restrict__ out, int M, int N, int K, int nbn)
{
    __shared__ int8_t lds_a[4][BM * BKB];   // 4 x 16 KB
    __shared__ int8_t lds_b[4][BN * BKB];   // 4 x 16 KB

    const int tid  = threadIdx.x;
    const int lane = tid & 63;
    const int wave = tid >> 6;

    // ---- XCD-aware block swizzle (nwg = 1376, divisible by 8) ----
    int bid = blockIdx.x;
    const int nwg = gridDim.x;
    if ((nwg & 7) == 0) bid = (bid & 7) * (nwg >> 3) + (bid >> 3);
    const int bm = bid / nbn;
    const int bn = bid - bm * nbn;

    // ---- staging: thread -> rows (tid>>2) + 128j, phys chunk tid&3 ----
    // stored logical chunk = (phys - (row>>1)) & 3; (row>>1)&3 == (tid>>3)&3 (j-free:
    // row = (tid>>2)+128j -> row>>1 = (tid>>3)+64j, 64j mod 4 = 0).
    const int srow  = tid >> 2;                                       // 0..127
    const int skoff = ((((tid & 3) - ((tid >> 3) & 3)) & 3) << 4);    // inverse swizzle
    const int8_t* gA = x + ((size_t)bm * BM + srow) * K + skoff;
    const int8_t* gB = w + ((size_t)bn * BN + srow) * K + skoff;
    const int ldst = tid * 16;    // == (tid>>2)*64 + (tid&3)*16 : row-major slot

    // ---- per-wave tile: 128 (M) x 64 (N) ----
    const int wr  = (wave >> 2) * 128;
    const int wc  = (wave & 3) * 64;
    const int l31 = lane & 31;
    const int q2  = lane >> 5;
    const int cq  = (l31 >> 1) & 3;   // (row>>1)&3 for this lane's frag rows

    i32x16 acc[4][2] = {};

    const int NT = K / BKB;           // 64

#define STAGE(T, BUF) { const size_t kk = (size_t)(T) * BKB;                          \
    async16(gA + kk,                    &lds_a[BUF][ldst]);                           \
    async16(gA + (size_t)128 * K + kk,  &lds_a[BUF][8192 + ldst]);                    \
    async16(gB + kk,                    &lds_b[BUF][ldst]);                           \
    async16(gB + (size_t)128 * K + kk,  &lds_b[BUF][8192 + ldst]); }

// read the 6 fragments (4 A + 2 B) of k-sub KS into frag slot S
#define READF(S, KS) {                                                                \
    const int ck_ = ((((KS) * 2 + q2) + cq) & 3) << 4;                                \
    _Pragma("unroll") for (int f = 0; f < 4; ++f)                                     \
        af[S][f] = *(const i32x4*)(la + ((wr + f * 32 + l31) << 6) + ck_);            \
    _Pragma("unroll") for (int f = 0; f < 2; ++f)                                     \
        bf[S][f] = *(const i32x4*)(lb + ((wc + f * 32 + l31) << 6) + ck_); }

    // ---- prologue: stage tiles 0,1,2 into bufs 0,1,2 ----
    STAGE(0, 0);
    STAGE(1, 1);
    STAGE(2, 2);

    for (int t = 0; t < NT; ++t) {
        const int cb = t & 3;

        __builtin_amdgcn_s_barrier();            // all waves done reading buf[(t-1)&3]
        __builtin_amdgcn_sched_barrier(0);       // pin STAGE below the barrier

        if (t + 3 < NT) STAGE(t + 3, (t + 3) & 3);

        // derived counted wait: tile t's 4 loads are the oldest outstanding
        const int rem = NT - 1 - t;              // tiles with possibly-in-flight loads
        if      (rem >= 3) asm volatile("s_waitcnt vmcnt(12)" ::: "memory");
        else if (rem == 2) asm volatile("s_waitcnt vmcnt(8)"  ::: "memory");
        else if (rem == 1) asm volatile("s_waitcnt vmcnt(4)"  ::: "memory");
        else               asm volatile("s_waitcnt vmcnt(0)"  ::: "memory");

        const int8_t* la = lds_a[cb];
        const int8_t* lb = lds_b[cb];

        i32x4 af[2][4], bf[2][2];
        READF(0, 0);
        READF(1, 1);

#pragma unroll
        for (int ks = 0; ks < 2; ++ks) {
            __builtin_amdgcn_s_setprio(1);
#pragma unroll
            for (int mf = 0; mf < 4; ++mf)
#pragma unroll
                for (int nf = 0; nf < 2; ++nf)
                    acc[mf][nf] = __builtin_amdgcn_mfma_i32_32x32x32_i8(
                        af[ks][mf], bf[ks][nf], acc[mf][nf], 0, 0, 0);
            __builtin_amdgcn_s_setprio(0);
        }
    }

    // ---- epilogue: y = alpha*acc + bias; y*sigmoid(y); fp32 store ----
    const float alpha = *alpha_p;
    const int rowb = bm * BM + wr;
    const int colb = bn * BN + wc;
#pragma unroll
    for (int nf = 0; nf < 2; ++nf) {
        const int col = colb + nf * 32 + l31;
        const float bv = bias[col];
#pragma unroll
        for (int mf = 0; mf < 4; ++mf) {
#pragma unroll
            for (int r = 0; r < 16; ++r) {
                const int row = rowb + mf * 32 + (r & 3) + ((r >> 2) << 3) + (q2 << 2);
                float y = fmaf(alpha, (float)acc[mf][nf][r], bv);
                out[(size_t)row * N + col] = y / (1.0f + __expf(-y));
            }
        }
    }
}

extern "C" void kernel_launch(void* const* d_in, const int* in_sizes, int n_in,
                              void* d_out, int out_size, void* d_ws, size_t ws_size,
                              hipStream_t stream) {
    const int*   x32   = (const int*)d_in[0];     // integer inputs arrive as int32
    const int*   w32   = (const int*)d_in[1];
    const float* bias  = (const float*)d_in[2];
    const float* alpha = (const float*)d_in[3];
    float*       out   = (float*)d_out;

    const int N = in_sizes[2];             // 11008
    const int K = in_sizes[1] / N;         // 4096
    const int M = in_sizes[0] / K;         // 8192

    // pack into workspace: [x8 (M*K)] [w8 (N*K)]
    int8_t* x8 = (int8_t*)d_ws;
    int8_t* w8 = x8 + (size_t)M * K;

    const int nx4 = (int)(((size_t)M * K) / 4);
    const int nw4 = (int)(((size_t)N * K) / 4);
    pack_both<<<2048, 256, 0, stream>>>((const int4*)x32, (int*)x8, nx4,
                                        (const int4*)w32, (int*)w8, nw4);

    const int nbm = M / BM, nbn = N / BN;  // 32, 43 -> 1376 blocks (divisible by 8)
    w8a8_silu_kernel<<<nbm * nbn, 512, 0, stream>>>(x8, w8, bias, alpha, out, M, N, K, nbn);
}